// Round 2
// baseline (496.996 us; speedup 1.0000x reference)
//
#include <hip/hip_runtime.h>
#include <hip/hip_bf16.h>

// HodgkinHuxley-like 7-state ODE scan: T=500 sequential steps, N=20000
// independent neurons. 1 thread = 1 neuron; state lives in registers;
// per-step the thread reads i_inj[t*N+n] (depth-8 register prefetch) and
// writes 7 coalesced output streams out[t*7*N + s*N + n].
//
// block=64: only 20000 threads exist -> 313 blocks spread across 256 CUs.
// 500 = 62*8 + 4: main loop is 62 branch-free 8-step blocks, then a 4-step
// tail; prefetch index is clamped (not branched) to stay in bounds.

#define TSTEPS 500
#define NNEUR  20000
#define DTS    0.1f

__device__ __forceinline__ float sigf(float z) {
    // jax.nn.sigmoid in f32; accurate expf to track the numpy reference.
    return 1.0f / (1.0f + expf(-z));
}

__global__ __launch_bounds__(64, 1)
void hh_kernel(const float* __restrict__ i_inj,
               const float* __restrict__ x0,
               const float* __restrict__ prm,
               float* __restrict__ out)
{
    const int n = blockIdx.x * 64 + threadIdx.x;
    if (n >= NNEUR) return;

    // params (PNAMES order)
    const float decay_ca = prm[0],  rho_ca  = prm[1];
    const float p_tau = prm[2],  p_scale = prm[3],  p_mdp = prm[4];
    const float q_tau = prm[5],  q_scale = prm[6],  q_mdp = prm[7];
    const float n_tau = prm[8],  n_scale = prm[9],  n_mdp = prm[10];
    const float f_tau = prm[11], f_scale = prm[12], f_mdp = prm[13];
    const float e_tau = prm[14], e_scale = prm[15], e_mdp = prm[16];
    const float h_alpha = prm[17], h_scale = prm[18], h_mdp = prm[19];
    const float C_m = prm[20], g_Ca = prm[21], g_Ks = prm[22];
    const float g_Kf = prm[23], g_L = prm[24];
    const float E_Ca = prm[25], E_K = prm[26], E_L = prm[27];

    // loop-invariant derived constants (uniform -> SGPRs)
    const float inv_dt    = 1.0f / DTS;
    const float dtC       = DTS / C_m;
    const float inv_decay = 1.0f / decay_ca;

    const float cf_p = p_tau * DTS / (p_tau + DTS), is_p = 1.0f / p_scale, it_p = 1.0f / p_tau;
    const float cf_q = q_tau * DTS / (q_tau + DTS), is_q = 1.0f / q_scale, it_q = 1.0f / q_tau;
    const float cf_n = n_tau * DTS / (n_tau + DTS), is_n = 1.0f / n_scale, it_n = 1.0f / n_tau;
    const float cf_f = f_tau * DTS / (f_tau + DTS), is_f = 1.0f / f_scale, it_f = 1.0f / f_tau;
    const float cf_e = e_tau * DTS / (e_tau + DTS), is_e = 1.0f / e_scale, it_e = 1.0f / e_tau;
    const float is_h = 1.0f / h_scale;

    // initial state
    float V   = x0[0 * NNEUR + n];
    float p   = x0[1 * NNEUR + n];
    float q   = x0[2 * NNEUR + n];
    float nn  = x0[3 * NNEUR + n];
    float e   = x0[4 * NNEUR + n];
    float f   = x0[5 * NNEUR + n];
    float cac = x0[6 * NNEUR + n];

#define HH_STEP(t, cur)                                                        \
    {                                                                          \
        const float hs = sigf((cac - h_mdp) * is_h);                           \
        const float h  = 1.0f + (hs - 1.0f) * h_alpha;                         \
        const float geh = g_Ca * e * e * f * h;                                \
        const float i_ca = geh * (V - E_Ca);                                   \
        const float i_ks = g_Ks * nn * (V - E_K);                              \
        const float p2   = p * p;                                              \
        const float i_kf = g_Kf * p2 * p2 * q * (V - E_K);                     \
        const float i_l  = g_L * (V - E_L);                                    \
        V = V + ((cur) - i_ca - i_ks - i_kf - i_l) * dtC;                      \
        const float i_ca2 = geh * (V - E_Ca);                                  \
        cac = cac + (-i_ca2 * rho_ca - cac * inv_decay) * DTS;                 \
        p  = cf_p * (p  * inv_dt + sigf((V - p_mdp) * is_p) * it_p);           \
        q  = cf_q * (q  * inv_dt + sigf((V - q_mdp) * is_q) * it_q);           \
        e  = cf_e * (e  * inv_dt + sigf((V - e_mdp) * is_e) * it_e);           \
        f  = cf_f * (f  * inv_dt + sigf((V - f_mdp) * is_f) * it_f);           \
        nn = cf_n * (nn * inv_dt + sigf((V - n_mdp) * is_n) * it_n);           \
        const size_t base = (size_t)(t) * (7 * NNEUR) + n;                     \
        out[base]             = V;                                             \
        out[base + 1 * NNEUR] = p;                                             \
        out[base + 2 * NNEUR] = q;                                             \
        out[base + 3 * NNEUR] = nn;                                            \
        out[base + 4 * NNEUR] = e;                                             \
        out[base + 5 * NNEUR] = f;                                             \
        out[base + 6 * NNEUR] = cac;                                           \
    }

    // depth-8 i_inj prefetch pipeline
    float buf[8];
#pragma unroll
    for (int j = 0; j < 8; ++j)
        buf[j] = i_inj[(size_t)j * NNEUR + n];

    // 62 full 8-step blocks (t = 0..495), branch-free
    for (int t0 = 0; t0 < TSTEPS - 8; t0 += 8) {
        float nbuf[8];
#pragma unroll
        for (int j = 0; j < 8; ++j) {
            int tt = t0 + 8 + j;
            tt = tt < TSTEPS ? tt : TSTEPS - 1;   // clamp, no branch; dummy value unused
            nbuf[j] = i_inj[(size_t)tt * NNEUR + n];
        }
#pragma unroll
        for (int j = 0; j < 8; ++j)
            HH_STEP(t0 + j, buf[j]);
#pragma unroll
        for (int j = 0; j < 8; ++j)
            buf[j] = nbuf[j];
    }

    // tail: last 4 steps (t = 496..499), data already in buf[0..3]
#pragma unroll
    for (int j = 0; j < 4; ++j)
        HH_STEP(TSTEPS - 4 + j, buf[j]);

#undef HH_STEP
}

extern "C" void kernel_launch(void* const* d_in, const int* in_sizes, int n_in,
                              void* d_out, int out_size, void* d_ws, size_t ws_size,
                              hipStream_t stream) {
    const float* i_inj  = (const float*)d_in[0];
    const float* x0     = (const float*)d_in[1];
    const float* params = (const float*)d_in[2];
    float* out = (float*)d_out;

    const int block = 64;
    const int grid  = (NNEUR + block - 1) / block;  // 313
    hipLaunchKernelGGL(hh_kernel, dim3(grid), dim3(block), 0, stream,
                       i_inj, x0, params, out);
}

// Round 6
// 396.047 us; speedup vs baseline: 1.2549x; 1.2549x over previous
//
#include <hip/hip_runtime.h>
#include <hip/hip_bf16.h>

// HodgkinHuxley-like 7-state ODE scan: T=500 sequential steps, N=20000
// independent neurons. 1 thread = 1 neuron; state in registers; per step
// read i_inj[t*N+n] (depth-8 register prefetch), write 7 coalesced streams.
//
// Hardware sigmoid: libm expf (~25 instr) + IEEE divide (~10 instr)
// x6 sigmoids dominated round 2's ~450 instr/step (261us, VALU-issue-bound
// at 1 wave/SIMD). sig(z) = v_rcp(1 + v_exp2(-z*log2e)) is 3 instr, ~1-2 ulp.
// Gate update folded to 2 FMAs: r = A_r*r + B_r*sig(...).

#define TSTEPS 500
#define NNEUR  20000
#define DTS    0.1f
#define LOG2E  1.442695040888963f

__device__ __forceinline__ float sigf(float z) {
    // sigmoid(z) = 1/(1+exp(-z)) via hardware v_exp_f32 / v_rcp_f32 (~1-2 ulp)
    const float e = __builtin_amdgcn_exp2f(z * -LOG2E);
    return __builtin_amdgcn_rcpf(1.0f + e);
}

__global__ __launch_bounds__(64, 1)
void hh_kernel(const float* __restrict__ i_inj,
               const float* __restrict__ x0,
               const float* __restrict__ prm,
               float* __restrict__ out)
{
    const int n = blockIdx.x * 64 + threadIdx.x;
    if (n >= NNEUR) return;

    // params (PNAMES order)
    const float decay_ca = prm[0],  rho_ca  = prm[1];
    const float p_tau = prm[2],  p_scale = prm[3],  p_mdp = prm[4];
    const float q_tau = prm[5],  q_scale = prm[6],  q_mdp = prm[7];
    const float n_tau = prm[8],  n_scale = prm[9],  n_mdp = prm[10];
    const float f_tau = prm[11], f_scale = prm[12], f_mdp = prm[13];
    const float e_tau = prm[14], e_scale = prm[15], e_mdp = prm[16];
    const float h_alpha = prm[17], h_scale = prm[18], h_mdp = prm[19];
    const float C_m = prm[20], g_Ca = prm[21], g_Ks = prm[22];
    const float g_Kf = prm[23], g_L = prm[24];
    const float E_Ca = prm[25], E_K = prm[26], E_L = prm[27];

    // loop-invariant derived constants (uniform -> scalar regs)
    const float inv_dt    = 1.0f / DTS;
    const float dtC       = DTS / C_m;
    const float inv_decay = 1.0f / decay_ca;

    // gate(x) = cf*(x/dt + sig/tau) = A*x + B*sig,  cf = tau*dt/(tau+dt)
    const float cf_p = p_tau * DTS / (p_tau + DTS);
    const float cf_q = q_tau * DTS / (q_tau + DTS);
    const float cf_n = n_tau * DTS / (n_tau + DTS);
    const float cf_f = f_tau * DTS / (f_tau + DTS);
    const float cf_e = e_tau * DTS / (e_tau + DTS);
    const float A_p = cf_p * inv_dt, B_p = cf_p / p_tau, is_p = 1.0f / p_scale;
    const float A_q = cf_q * inv_dt, B_q = cf_q / q_tau, is_q = 1.0f / q_scale;
    const float A_n = cf_n * inv_dt, B_n = cf_n / n_tau, is_n = 1.0f / n_scale;
    const float A_f = cf_f * inv_dt, B_f = cf_f / f_tau, is_f = 1.0f / f_scale;
    const float A_e = cf_e * inv_dt, B_e = cf_e / e_tau, is_e = 1.0f / e_scale;
    const float is_h = 1.0f / h_scale;

    // initial state
    float V   = x0[0 * NNEUR + n];
    float p   = x0[1 * NNEUR + n];
    float q   = x0[2 * NNEUR + n];
    float nn  = x0[3 * NNEUR + n];
    float e   = x0[4 * NNEUR + n];
    float f   = x0[5 * NNEUR + n];
    float cac = x0[6 * NNEUR + n];

#define HH_STEP(t, cur)                                                        \
    {                                                                          \
        const float hs  = sigf((cac - h_mdp) * is_h);                          \
        const float h   = 1.0f + (hs - 1.0f) * h_alpha;                        \
        const float geh = g_Ca * e * e * f * h;                                \
        const float p2  = p * p;                                               \
        const float ik  = (g_Ks * nn + g_Kf * p2 * p2 * q) * (V - E_K);        \
        V = V + ((cur) - geh * (V - E_Ca) - ik - g_L * (V - E_L)) * dtC;       \
        cac = cac + (-geh * (V - E_Ca) * rho_ca - cac * inv_decay) * DTS;      \
        p  = A_p * p  + B_p * sigf((V - p_mdp) * is_p);                        \
        q  = A_q * q  + B_q * sigf((V - q_mdp) * is_q);                        \
        e  = A_e * e  + B_e * sigf((V - e_mdp) * is_e);                        \
        f  = A_f * f  + B_f * sigf((V - f_mdp) * is_f);                        \
        nn = A_n * nn + B_n * sigf((V - n_mdp) * is_n);                        \
        const size_t base = (size_t)(t) * (7 * NNEUR) + n;                     \
        out[base]             = V;                                             \
        out[base + 1 * NNEUR] = p;                                             \
        out[base + 2 * NNEUR] = q;                                             \
        out[base + 3 * NNEUR] = nn;                                            \
        out[base + 4 * NNEUR] = e;                                             \
        out[base + 5 * NNEUR] = f;                                             \
        out[base + 6 * NNEUR] = cac;                                           \
    }

    // depth-8 i_inj prefetch pipeline
    float buf[8];
#pragma unroll
    for (int j = 0; j < 8; ++j)
        buf[j] = i_inj[(size_t)j * NNEUR + n];

    // 62 full 8-step blocks (t = 0..495), branch-free
    for (int t0 = 0; t0 < TSTEPS - 8; t0 += 8) {
        float nbuf[8];
#pragma unroll
        for (int j = 0; j < 8; ++j) {
            int tt = t0 + 8 + j;
            tt = tt < TSTEPS ? tt : TSTEPS - 1;   // clamp, no branch; dummy unused
            nbuf[j] = i_inj[(size_t)tt * NNEUR + n];
        }
#pragma unroll
        for (int j = 0; j < 8; ++j)
            HH_STEP(t0 + j, buf[j]);
#pragma unroll
        for (int j = 0; j < 8; ++j)
            buf[j] = nbuf[j];
    }

    // tail: last 4 steps (t = 496..499)
#pragma unroll
    for (int j = 0; j < 4; ++j)
        HH_STEP(TSTEPS - 4 + j, buf[j]);

#undef HH_STEP
}

extern "C" void kernel_launch(void* const* d_in, const int* in_sizes, int n_in,
                              void* d_out, int out_size, void* d_ws, size_t ws_size,
                              hipStream_t stream) {
    const float* i_inj  = (const float*)d_in[0];
    const float* x0     = (const float*)d_in[1];
    const float* params = (const float*)d_in[2];
    float* out = (float*)d_out;

    const int block = 64;
    const int grid  = (NNEUR + block - 1) / block;  // 313
    hipLaunchKernelGGL(hh_kernel, dim3(grid), dim3(block), 0, stream,
                       i_inj, x0, params, out);
}

// Round 7
// 360.754 us; speedup vs baseline: 1.3777x; 1.0978x over previous
//
#include <hip/hip_runtime.h>
#include <hip/hip_bf16.h>

// HodgkinHuxley 7-state ODE scan: T=500 sequential steps, N=20000 neurons.
// 1 thread = 1 neuron; state in registers. Occupancy is structurally capped
// at ~313 waves (3.6%) -> wall time ~ per-step instruction count.
//
// Round 7: instruction-count shave.
//  - sigmoid arg in ONE fma: exp2arg = fma(x, -is*log2e, mdp*is*log2e)
//  - sig = v_rcp(1 + v_exp2(arg))                       (2 trans ops)
//  - V-update refactored: V = fma(num, kV, V), num = t3 - gtot*V
//  - h folded with g_Ca: hg = fma(hs, a*gCa, (1-a)*gCa)
//  - gate update: r = fma(A_r, r, B_r*sig)
//  - 32-bit incremental byte offsets vs 8 SGPR stream bases (1 v_add/step)
// ~64 instr/step (12 trans) vs ~95 before.

#define TSTEPS 500
#define NNEUR  20000
#define DTS    0.1f
#define LOG2E  1.442695040888963f

__device__ __forceinline__ float hw_exp2(float x) { return __builtin_amdgcn_exp2f(x); }
__device__ __forceinline__ float hw_rcp(float x)  { return __builtin_amdgcn_rcpf(x); }

__global__ __launch_bounds__(64, 1)
void hh_kernel(const float* __restrict__ i_inj,
               const float* __restrict__ x0,
               const float* __restrict__ prm,
               float* __restrict__ out)
{
    const int n = blockIdx.x * 64 + threadIdx.x;
    if (n >= NNEUR) return;

    // params (PNAMES order)
    const float decay_ca = prm[0],  rho_ca  = prm[1];
    const float p_tau = prm[2],  p_scale = prm[3],  p_mdp = prm[4];
    const float q_tau = prm[5],  q_scale = prm[6],  q_mdp = prm[7];
    const float n_tau = prm[8],  n_scale = prm[9],  n_mdp = prm[10];
    const float f_tau = prm[11], f_scale = prm[12], f_mdp = prm[13];
    const float e_tau = prm[14], e_scale = prm[15], e_mdp = prm[16];
    const float h_alpha = prm[17], h_scale = prm[18], h_mdp = prm[19];
    const float C_m = prm[20], g_Ca = prm[21], g_Ks = prm[22];
    const float g_Kf = prm[23], g_L = prm[24];
    const float E_Ca = prm[25], E_K = prm[26], E_L = prm[27];

    // ---- loop-invariant folded constants (uniform -> SGPRs) ----
    const float kV    = DTS / C_m;          // dt/C_m
    const float cLEL  = g_L * E_L;          // const part of num
    const float cKeep = 1.0f - DTS / decay_ca;
    const float cRho  = rho_ca * DTS;

    // sigmoid arg: exp2arg(x; mdp, is) = -(x-mdp)*is*log2e = fma(x, za, zb)
    const float isH = 1.0f / h_scale;
    const float zaH = -LOG2E * isH, zbH = h_mdp * isH * LOG2E;
    const float aG  = h_alpha * g_Ca;              // h*g_Ca = fma(hs, aG, bG)
    const float bG  = (1.0f - h_alpha) * g_Ca;

#define GATECONST(r, tau, scale, mdp)                                          \
    const float cf_##r = (tau) * DTS / ((tau) + DTS);                          \
    const float A_##r  = cf_##r / DTS;                                         \
    const float B_##r  = cf_##r / (tau);                                       \
    const float za##r  = -LOG2E / (scale);                                     \
    const float zb##r  = (mdp) * LOG2E / (scale);
    GATECONST(p, p_tau, p_scale, p_mdp)
    GATECONST(q, q_tau, q_scale, q_mdp)
    GATECONST(n, n_tau, n_scale, n_mdp)
    GATECONST(f, f_tau, f_scale, f_mdp)
    GATECONST(e, e_tau, e_scale, e_mdp)
#undef GATECONST

    // ---- initial state ----
    float V   = x0[0 * NNEUR + n];
    float p   = x0[1 * NNEUR + n];
    float q   = x0[2 * NNEUR + n];
    float nn  = x0[3 * NNEUR + n];
    float e   = x0[4 * NNEUR + n];
    float f   = x0[5 * NNEUR + n];
    float cac = x0[6 * NNEUR + n];

    // ---- stream base pointers (SGPR pairs) + 32-bit byte offsets ----
    float* const oV = out + 0 * NNEUR;
    float* const oP = out + 1 * NNEUR;
    float* const oQ = out + 2 * NNEUR;
    float* const oN = out + 3 * NNEUR;
    float* const oE = out + 4 * NNEUR;
    float* const oF = out + 5 * NNEUR;
    float* const oC = out + 6 * NNEUR;
    unsigned boff = (unsigned)n * 4u;                 // output byte offset
    const unsigned BSTEP = 7u * NNEUR * 4u;           // per-step advance
    unsigned ioff = (unsigned)n * 4u;                 // i_inj byte offset of t0
    const unsigned ISTEP = (unsigned)NNEUR * 4u;

#define LD(off)  (*(const float*)((const char*)i_inj + (off)))
#define ST(ptr)  (*(float*)((char*)(ptr) + boff))

#define HH_STEP(cur)                                                           \
    {                                                                          \
        /* h & Ca conductance from OLD cac,e,f */                              \
        const float hs  = hw_rcp(1.0f + hw_exp2(fmaf(cac, zaH, zbH)));         \
        const float hg  = fmaf(hs, aG, bG);          /* h*g_Ca */              \
        const float geh = (e * e) * (f * hg);                                  \
        const float p2  = p * p;                                               \
        const float g   = fmaf(g_Kf, (p2 * p2) * q, g_Ks * nn);                \
        const float gtot = geh + g + g_L;                                      \
        const float t3  = fmaf(g, E_K, fmaf(geh, E_Ca, (cur) + cLEL));         \
        const float num = fmaf(-gtot, V, t3);                                  \
        V = fmaf(num, kV, V);                                                  \
        /* cac with I_Ca at UPDATED V */                                       \
        const float ica2 = geh * (V - E_Ca);                                   \
        cac = fmaf(cac, cKeep, -(ica2 * cRho));                                \
        /* gates at updated V */                                               \
        const float sp = hw_rcp(1.0f + hw_exp2(fmaf(V, zap, zbp)));            \
        const float sq = hw_rcp(1.0f + hw_exp2(fmaf(V, zaq, zbq)));            \
        const float se = hw_rcp(1.0f + hw_exp2(fmaf(V, zae, zbe)));            \
        const float sf = hw_rcp(1.0f + hw_exp2(fmaf(V, zaf, zbf)));            \
        const float sn = hw_rcp(1.0f + hw_exp2(fmaf(V, zan, zbn)));            \
        p  = fmaf(A_p, p,  B_p * sp);                                          \
        q  = fmaf(A_q, q,  B_q * sq);                                          \
        e  = fmaf(A_e, e,  B_e * se);                                          \
        f  = fmaf(A_f, f,  B_f * sf);                                          \
        nn = fmaf(A_n, nn, B_n * sn);                                          \
        ST(oV) = V;  ST(oP) = p;  ST(oQ) = q;  ST(oN) = nn;                    \
        ST(oE) = e;  ST(oF) = f;  ST(oC) = cac;                                \
        boff += BSTEP;                                                         \
    }

    // depth-8 i_inj prefetch pipeline
    float buf[8];
#pragma unroll
    for (int j = 0; j < 8; ++j)
        buf[j] = LD(ioff + (unsigned)j * ISTEP);
    ioff += 8u * ISTEP;

    // 62 full 8-step blocks (t = 0..495), branch-free
    for (int t0 = 0; t0 < TSTEPS - 8; t0 += 8) {
        float nbuf[8];
#pragma unroll
        for (int j = 0; j < 8; ++j) {
            // clamp next-block offset to last valid row (dummy value unused)
            unsigned o = ioff + (unsigned)j * ISTEP;
            const unsigned omax = (unsigned)(TSTEPS - 1) * ISTEP + (unsigned)n * 4u;
            o = o < omax ? o : omax;
            nbuf[j] = LD(o);
        }
        ioff += 8u * ISTEP;
#pragma unroll
        for (int j = 0; j < 8; ++j)
            HH_STEP(buf[j]);
#pragma unroll
        for (int j = 0; j < 8; ++j)
            buf[j] = nbuf[j];
    }

    // tail: last 4 steps (t = 496..499)
#pragma unroll
    for (int j = 0; j < 4; ++j)
        HH_STEP(buf[j]);

#undef HH_STEP
#undef LD
#undef ST
}

extern "C" void kernel_launch(void* const* d_in, const int* in_sizes, int n_in,
                              void* d_out, int out_size, void* d_ws, size_t ws_size,
                              hipStream_t stream) {
    const float* i_inj  = (const float*)d_in[0];
    const float* x0     = (const float*)d_in[1];
    const float* params = (const float*)d_in[2];
    float* out = (float*)d_out;

    const int block = 64;
    const int grid  = (NNEUR + block - 1) / block;  // 313
    hipLaunchKernelGGL(hh_kernel, dim3(grid), dim3(block), 0, stream,
                       i_inj, x0, params, out);
}